// Round 1
// 1285.677 us; speedup vs baseline: 1.0705x; 1.0705x over previous
//
#include <hip/hip_runtime.h>
#include <math.h>

#define NN 100000
#define FIN 500
#define HIDN 64
#define KF 5
#define DORD 10

typedef unsigned short ushort_t;

struct Tables { float sinc[KF][DORD+1]; float cosc[KF][DORD+1]; };

// bf16 helpers: low/high halves of a packed uint, RNE pack
__device__ inline float bl(unsigned u) { return __uint_as_float(u << 16); }
__device__ inline float bh(unsigned u) { return __uint_as_float(u & 0xffff0000u); }
__device__ inline unsigned short bf16_rne(float x) {
    unsigned u = __float_as_uint(x);
    return (unsigned short)((u + 0x7fffu + ((u >> 16) & 1u)) >> 16);
}
__device__ inline unsigned pack_bf16x2(float a, float b) {
    return (unsigned)bf16_rne(a) | ((unsigned)bf16_rne(b) << 16);
}

// ---- coeff[d] = sum_k alpha[k]*sinc[k][d] + beta[k]*cosc[k][d] ----
__global__ void coeff_kernel(const float* __restrict__ alpha, const float* __restrict__ beta,
                             Tables tb, float* __restrict__ coeff) {
    int d = threadIdx.x;
    if (d <= DORD) {
        float c = 0.f;
        #pragma unroll
        for (int k = 0; k < KF; ++k)
            c += alpha[k] * tb.sinc[k][d] + beta[k] * tb.cosc[k][d];
        coeff[d] = c;
    }
}

// Buckets are 256 nodes wide (power of 2): bucket = v >> 8, offset = v & 255.
// nb = ceil(n/256) must be <= 512 (n <= 131072; harness n = 100000 -> nb = 391).
#define CHUNK 4096

// ---- pass 0: per-chunk dst-bucket AND src-bucket histograms (no global atomics) ----
__global__ __launch_bounds__(256) void hist_kernel(
    const int* __restrict__ src, const int* __restrict__ dst,
    int* __restrict__ histD, int* __restrict__ histS, int E, int nb) {
    __shared__ int hD[512];
    __shared__ int hS[512];
    for (int i = threadIdx.x; i < 512; i += 256) { hD[i] = 0; hS[i] = 0; }
    __syncthreads();
    int base = blockIdx.x * CHUNK;
    int end = base + CHUNK; if (end > E) end = E;
    for (int e = base + threadIdx.x; e < end; e += 256) {
        int s = src[e], d = dst[e];
        if (s != d) {
            atomicAdd(&hD[d >> 8], 1);
            atomicAdd(&hS[s >> 8], 1);
        }
    }
    __syncthreads();
    size_t ro = (size_t)blockIdx.x * 512;
    for (int i = threadIdx.x; i < nb; i += 256) {
        histD[ro + i] = hD[i];
        histS[ro + i] = hS[i];
    }
}

// ---- pass 0.5a: per-bucket exclusive scan over chunks (in place) + bucket totals ----
// grid = 2*nb blocks of 512 threads; first nb blocks scan histD, rest histS.
__global__ __launch_bounds__(512) void scanA_kernel(
    int* __restrict__ histD, int* __restrict__ histS,
    int* __restrict__ totD, int* __restrict__ totS, int nchunk, int nb) {
    __shared__ int tmp[512];
    int x = blockIdx.x;
    int* hist; int* tot; int b;
    if (x < nb) { hist = histD; tot = totD; b = x; }
    else        { hist = histS; tot = totS; b = x - nb; }
    int t = threadIdx.x;
    int carry = 0;
    for (int c0 = 0; c0 < nchunk; c0 += 512) {
        int c = c0 + t;
        tmp[t] = (c < nchunk) ? hist[(size_t)c * 512 + b] : 0;
        __syncthreads();
        for (int off = 1; off < 512; off <<= 1) {
            int add = (t >= off) ? tmp[t - off] : 0;
            __syncthreads();
            tmp[t] += add;
            __syncthreads();
        }
        if (c < nchunk) hist[(size_t)c * 512 + b] = carry + ((t > 0) ? tmp[t - 1] : 0);
        carry += tmp[511];
        __syncthreads();
    }
    if (t == 0) tot[b] = carry;
}

// ---- pass 0.5b: exclusive scan over bucket totals -> absolute bucket bases ----
__global__ __launch_bounds__(512) void scanB_kernel(
    const int* __restrict__ totD, const int* __restrict__ totS,
    int* __restrict__ offD, int* __restrict__ offS, int nb) {
    __shared__ int tmp[512];
    int t = threadIdx.x;
    tmp[t] = (t < nb) ? totD[t] : 0;
    __syncthreads();
    for (int off = 1; off < 512; off <<= 1) {
        int add = (t >= off) ? tmp[t - off] : 0;
        __syncthreads();
        tmp[t] += add;
        __syncthreads();
    }
    if (t < nb) offD[t] = (t > 0) ? tmp[t - 1] : 0;
    if (t == nb - 1) offD[nb] = tmp[t];
    __syncthreads();
    tmp[t] = (t < nb) ? totS[t] : 0;
    __syncthreads();
    for (int off = 1; off < 512; off <<= 1) {
        int add = (t >= off) ? tmp[t - off] : 0;
        __syncthreads();
        tmp[t] += add;
        __syncthreads();
    }
    if (t < nb) offS[t] = (t > 0) ? tmp[t - 1] : 0;
    if (t == nb - 1) offS[nb] = tmp[t];
}

// ---- pass 1: scatter with precomputed deterministic cursors (LDS atomics only) ----
// binned entry packs src (low 24 bits, requires n < 2^24) and dst&255 (high 8 bits).
__global__ __launch_bounds__(256) void scatter_kernel(
    const int* __restrict__ src, const int* __restrict__ dst,
    const int* __restrict__ histD, const int* __restrict__ histS,
    const int* __restrict__ offD, const int* __restrict__ offS,
    unsigned* __restrict__ binned, unsigned char* __restrict__ srcbin, int E, int nb) {
    __shared__ int cD[512];
    __shared__ int cS[512];
    size_t ro = (size_t)blockIdx.x * 512;
    for (int i = threadIdx.x; i < nb; i += 256) {
        cD[i] = offD[i] + histD[ro + i];
        cS[i] = offS[i] + histS[ro + i];
    }
    __syncthreads();
    int base = blockIdx.x * CHUNK;
    int end = base + CHUNK; if (end > E) end = E;
    for (int e = base + threadIdx.x; e < end; e += 256) {
        int s = src[e], d = dst[e];
        if (s != d) {
            int pD = atomicAdd(&cD[d >> 8], 1);
            binned[pD] = (unsigned)s | ((unsigned)(d & 255) << 24);
            int pS = atomicAdd(&cS[s >> 8], 1);
            srcbin[pS] = (unsigned char)(s & 255);
        }
    }
}

// ---- pass 2a: one block owns one bucket: local indeg, scan, row_ptr, col ----
__global__ __launch_bounds__(256) void bucket_csr_kernel(
    const unsigned* __restrict__ binned, const int* __restrict__ offD,
    int* __restrict__ row_ptr, int* __restrict__ col, int n, int nb) {
    int b = blockIdx.x;
    int e0 = offD[b], e1 = offD[b + 1];
    int d0 = b << 8;
    int dn = n - d0; if (dn > 256) dn = 256;
    __shared__ int ind[256];
    __shared__ int cur[256];
    int t = threadIdx.x;
    ind[t] = 0;
    __syncthreads();
    for (int e = e0 + t; e < e1; e += 256) {
        unsigned p = binned[e];
        atomicAdd(&ind[p >> 24], 1);
    }
    __syncthreads();
    for (int off = 1; off < 256; off <<= 1) {
        int add = (t >= off) ? ind[t - off] : 0;
        __syncthreads();
        ind[t] += add;
        __syncthreads();
    }
    if (t < dn) {
        int excl = (t > 0) ? ind[t - 1] : 0;
        row_ptr[d0 + t] = e0 + excl;
        cur[t] = e0 + excl;
    }
    if (b == 0 && t == 0) row_ptr[n] = offD[nb];
    __syncthreads();
    for (int e = e0 + t; e < e1; e += 256) {
        unsigned p = binned[e];
        int pos = atomicAdd(&cur[p >> 24], 1);
        col[pos] = (int)(p & 0xFFFFFFu);
    }
}

// ---- pass 2b: out-degree per node from src-binned bytes -> dinv (no deg array) ----
__global__ __launch_bounds__(256) void dinv_count_kernel(
    const unsigned char* __restrict__ srcbin, const int* __restrict__ offS,
    float* __restrict__ dinv, int n, int nb) {
    __shared__ int ind[256];
    int b = blockIdx.x;
    int t = threadIdx.x;
    ind[t] = 0;
    __syncthreads();
    int e0 = offS[b], e1 = offS[b + 1];
    for (int e = e0 + t; e < e1; e += 256)
        atomicAdd(&ind[srcbin[e]], 1);
    __syncthreads();
    int i = (b << 8) + t;
    if (i < n) {
        int c = ind[t];
        dinv[i] = (c > 0) ? (1.0f / sqrtf((float)c)) : 0.f;
    }
}

// ---- GEMM1: H = relu(A[n,500] @ W[500,64] + b) ----
__global__ __launch_bounds__(256) void gemm1_kernel(
    const float* __restrict__ A, const float* __restrict__ W,
    const float* __restrict__ bias, float* __restrict__ H, int n) {
    __shared__ float sA[64][36];   // row-major A tile, padded
    __shared__ float sW[32][64];
    int t = threadIdx.x;
    int tx = t & 15, ty = t >> 4;
    int rowBase = blockIdx.x * 64;
    float acc[4][4] = {{0.f}};
    for (int k0 = 0; k0 < FIN; k0 += 32) {
        #pragma unroll
        for (int l = 0; l < 2; ++l) {
            int c = t + l * 256;
            int r = c >> 3, cc = (c & 7) * 4;
            int gr = rowBase + r, gk = k0 + cc;
            float4 v = make_float4(0.f, 0.f, 0.f, 0.f);
            if (gr < n && gk < FIN) v = *(const float4*)(A + (size_t)gr * FIN + gk);
            *(float4*)&sA[r][cc] = v;
        }
        #pragma unroll
        for (int l = 0; l < 2; ++l) {
            int c = t + l * 256;
            int r = c >> 4, cc = (c & 15) * 4;
            int gk = k0 + r;
            float4 v = make_float4(0.f, 0.f, 0.f, 0.f);
            if (gk < FIN) v = *(const float4*)(W + (size_t)gk * 64 + cc);
            *(float4*)&sW[r][cc] = v;
        }
        __syncthreads();
        #pragma unroll
        for (int kk = 0; kk < 32; ++kk) {
            float a[4], b[4];
            #pragma unroll
            for (int i = 0; i < 4; ++i) a[i] = sA[ty * 4 + i][kk];
            #pragma unroll
            for (int j = 0; j < 4; ++j) b[j] = sW[kk][tx * 4 + j];
            #pragma unroll
            for (int i = 0; i < 4; ++i)
                #pragma unroll
                for (int j = 0; j < 4; ++j)
                    acc[i][j] = fmaf(a[i], b[j], acc[i][j]);
        }
        __syncthreads();
    }
    #pragma unroll
    for (int i = 0; i < 4; ++i) {
        int gr = rowBase + ty * 4 + i;
        if (gr < n) {
            float4 o;
            o.x = fmaxf(acc[i][0] + bias[tx * 4 + 0], 0.f);
            o.y = fmaxf(acc[i][1] + bias[tx * 4 + 1], 0.f);
            o.z = fmaxf(acc[i][2] + bias[tx * 4 + 2], 0.f);
            o.w = fmaxf(acc[i][3] + bias[tx * 4 + 3], 0.f);
            *(float4*)(H + (size_t)gr * 64 + tx * 4) = o;
        }
    }
}

// ---- GEMM2: X = H @ W2 + b2 ; out = (1+coeff[0])*X ; ty0 = bf16(dinv ⊙ X) ----
__global__ __launch_bounds__(256) void gemm2_kernel(
    const float* __restrict__ H, const float* __restrict__ W2,
    const float* __restrict__ b2, const float* __restrict__ coeff,
    const float* __restrict__ dinv, ushort_t* __restrict__ ty0,
    float* __restrict__ out, int n) {
    __shared__ float sW[64 * 64];
    __shared__ float sb[64];
    int t = threadIdx.x;
    for (int i = t; i < 4096; i += 256) sW[i] = W2[i];
    if (t < 64) sb[t] = b2[t];
    __syncthreads();
    float c0p1 = 1.f + coeff[0];
    int lane = t & 63;
    int wid = t >> 6;
    int r0 = blockIdx.x * 128;
    int rend = r0 + 128; if (rend > n) rend = n;
    for (int r = r0 + wid; r < rend; r += 4) {
        float hv = H[(size_t)r * 64 + lane];
        float dr = dinv[r];
        float acc = sb[lane];
        #pragma unroll
        for (int k = 0; k < 64; ++k)
            acc = fmaf(__shfl(hv, k, 64), sW[k * 64 + lane], acc);
        ty0[(size_t)r * 64 + lane] = bf16_rne(dr * acc);
        out[(size_t)r * 64 + lane] = c0p1 * acc;
    }
}

// ---- SpMM hop (dinv-folded, bf16 state): one wave per dst row.
__global__ __launch_bounds__(256) void spmm_kernel(
    const int* __restrict__ row_ptr, const int* __restrict__ col,
    const float* __restrict__ dinv, const ushort_t* __restrict__ tyin,
    ushort_t* __restrict__ tyout, float* __restrict__ out,
    const float* __restrict__ coeff, int d, int n, int fuse_lsm) {
    int wave = (blockIdx.x * blockDim.x + threadIdx.x) >> 6;
    if (wave >= n) return;
    int lane = threadIdx.x & 63;
    int sub = lane >> 4;       // 0..3: which edge within a group of 4
    int fl = lane & 15;        // feature group: elems 4*fl .. 4*fl+3
    int e0 = row_ptr[wave], e1 = row_ptr[wave + 1];
    float ax = 0.f, ay = 0.f, az = 0.f, aw = 0.f;
    int e = e0 + sub;
    for (; e + 12 < e1; e += 16) {
        int s0 = col[e], s1 = col[e + 4], s2 = col[e + 8], s3 = col[e + 12];
        uint2 p0 = *(const uint2*)(tyin + (size_t)s0 * 64 + fl * 4);
        uint2 p1 = *(const uint2*)(tyin + (size_t)s1 * 64 + fl * 4);
        uint2 p2 = *(const uint2*)(tyin + (size_t)s2 * 64 + fl * 4);
        uint2 p3 = *(const uint2*)(tyin + (size_t)s3 * 64 + fl * 4);
        ax += (bl(p0.x) + bl(p1.x)) + (bl(p2.x) + bl(p3.x));
        ay += (bh(p0.x) + bh(p1.x)) + (bh(p2.x) + bh(p3.x));
        az += (bl(p0.y) + bl(p1.y)) + (bl(p2.y) + bl(p3.y));
        aw += (bh(p0.y) + bh(p1.y)) + (bh(p2.y) + bh(p3.y));
    }
    for (; e < e1; e += 4) {
        int s = col[e];
        uint2 p = *(const uint2*)(tyin + (size_t)s * 64 + fl * 4);
        ax += bl(p.x); ay += bh(p.x); az += bl(p.y); aw += bh(p.y);
    }
    #pragma unroll
    for (int off = 16; off <= 32; off <<= 1) {
        ax += __shfl_xor(ax, off, 64);
        ay += __shfl_xor(ay, off, 64);
        az += __shfl_xor(az, off, 64);
        aw += __shfl_xor(aw, off, 64);
    }
    float dr = dinv[wave];
    float cd = coeff[d];
    float tx_x = -dr * ax, tx_y = -dr * ay, tx_z = -dr * az, tx_w = -dr * aw;
    float4 o = *(const float4*)(out + (size_t)wave * 64 + fl * 4);
    o.x += cd * tx_x; o.y += cd * tx_y; o.z += cd * tx_z; o.w += cd * tx_w;
    if (!fuse_lsm) {
        if (sub == 0) {
            uint2 ty;
            ty.x = pack_bf16x2(dr * tx_x, dr * tx_y);
            ty.y = pack_bf16x2(dr * tx_z, dr * tx_w);
            *(uint2*)(tyout + (size_t)wave * 64 + fl * 4) = ty;
            *(float4*)(out + (size_t)wave * 64 + fl * 4) = o;
        }
    } else {
        float m = fmaxf(fmaxf(o.x, o.y), fmaxf(o.z, o.w));
        #pragma unroll
        for (int off = 1; off < 16; off <<= 1) m = fmaxf(m, __shfl_xor(m, off, 64));
        float s4 = expf(o.x - m) + expf(o.y - m) + expf(o.z - m) + expf(o.w - m);
        #pragma unroll
        for (int off = 1; off < 16; off <<= 1) s4 += __shfl_xor(s4, off, 64);
        float lse = m + logf(s4);
        o.x -= lse; o.y -= lse; o.z -= lse; o.w -= lse;
        if (sub == 0)
            *(float4*)(out + (size_t)wave * 64 + fl * 4) = o;
    }
}

extern "C" void kernel_launch(void* const* d_in, const int* in_sizes, int n_in,
                              void* d_out, int out_size, void* d_ws, size_t ws_size,
                              hipStream_t stream) {
    const float* feature = (const float*)d_in[0];
    const int*   edges   = (const int*)d_in[1];
    const float* W1      = (const float*)d_in[2];
    const float* b1      = (const float*)d_in[3];
    const float* W2      = (const float*)d_in[4];
    const float* b2      = (const float*)d_in[5];
    const float* alpha   = (const float*)d_in[6];
    const float* beta    = (const float*)d_in[7];
    float* out = (float*)d_out;

    const int n = in_sizes[0] / FIN;      // 100000
    const int E = in_sizes[1] / 2;        // 3200000
    const int* src = edges;
    const int* dst = edges + E;

    const int nb = (n + 255) >> 8;        // 391 buckets of 256 nodes
    const int nchunk = (E + CHUNK - 1) / CHUNK;

    // ---- workspace layout (256B aligned) ----
    char* ws = (char*)d_ws;
    size_t off = 0;
    auto alloc = [&](size_t bytes) { size_t o = off; off = (off + bytes + 255) & ~(size_t)255; return o; };
    float*         coeff   = (float*)        (ws + alloc(64 * 4));
    float*         dinv    = (float*)        (ws + alloc((size_t)n * 4));
    int*           row_ptr = (int*)          (ws + alloc(((size_t)n + 1) * 4));
    int*           offD    = (int*)          (ws + alloc(513 * 4));
    int*           offS    = (int*)          (ws + alloc(513 * 4));
    int*           totD    = (int*)          (ws + alloc(512 * 4));
    int*           totS    = (int*)          (ws + alloc(512 * 4));
    int*           histD   = (int*)          (ws + alloc((size_t)nchunk * 512 * 4));
    int*           histS   = (int*)          (ws + alloc((size_t)nchunk * 512 * 4));
    int*           col     = (int*)          (ws + alloc((size_t)E * 4));
    unsigned*      binned  = (unsigned*)     (ws + alloc((size_t)E * 4));
    unsigned char* srcbin  = (unsigned char*)(ws + alloc((size_t)E));
    float*         H       = (float*)        (ws + alloc((size_t)n * 64 * 4));
    ushort_t*      TyA     = (ushort_t*)     (ws + alloc((size_t)n * 64 * 2));
    ushort_t*      TyB     = (ushort_t*)     (ws + alloc((size_t)n * 64 * 2));

    // ---- host-side Taylor tables (deterministic, recomputed every call) ----
    Tables tb;
    for (int k = 0; k < KF; ++k) {
        double x = M_PI * (double)(k + 1);   // OMEGA = 1
        double p = 1.0, f = 1.0;
        for (int o = 0; o <= DORD; ++o) {
            if (o > 0) { p *= x; f *= (double)o; }
            double v = p / f;
            tb.cosc[k][o] = (o % 2 == 0) ? (float)((((o / 2) % 2 == 0) ? 1.0 : -1.0) * v) : 0.f;
            tb.sinc[k][o] = (o % 2 == 1) ? (float)(((((o - 1) / 2) % 2 == 0) ? 1.0 : -1.0) * v) : 0.f;
        }
    }

    coeff_kernel<<<1, 64, 0, stream>>>(alpha, beta, tb, coeff);

    hist_kernel<<<nchunk, 256, 0, stream>>>(src, dst, histD, histS, E, nb);
    scanA_kernel<<<2 * nb, 512, 0, stream>>>(histD, histS, totD, totS, nchunk, nb);
    scanB_kernel<<<1, 512, 0, stream>>>(totD, totS, offD, offS, nb);
    scatter_kernel<<<nchunk, 256, 0, stream>>>(src, dst, histD, histS, offD, offS,
                                               binned, srcbin, E, nb);
    bucket_csr_kernel<<<nb, 256, 0, stream>>>(binned, offD, row_ptr, col, n, nb);
    dinv_count_kernel<<<nb, 256, 0, stream>>>(srcbin, offS, dinv, n, nb);

    gemm1_kernel<<<(n + 63) / 64, 256, 0, stream>>>(feature, W1, b1, H, n);
    gemm2_kernel<<<(n + 127) / 128, 256, 0, stream>>>(H, W2, b2, coeff, dinv, TyA, out, n);

    const ushort_t* tin = TyA;
    ushort_t* bufs[2] = { TyB, TyA };
    for (int d = 1; d <= DORD; ++d) {
        ushort_t* tout = bufs[(d - 1) & 1];
        spmm_kernel<<<(n + 3) / 4, 256, 0, stream>>>(row_ptr, col, dinv, tin, tout, out,
                                                     coeff, d, n, d == DORD ? 1 : 0);
        tin = tout;
    }
}

// Round 2
// 1267.099 us; speedup vs baseline: 1.0862x; 1.0147x over previous
//
#include <hip/hip_runtime.h>
#include <math.h>

#define NN 100000
#define FIN 500
#define HIDN 64
#define KF 5
#define DORD 10
#define KPAD 512
#define NKT 8

typedef unsigned short ushort_t;
typedef __attribute__((ext_vector_type(8))) short short8v;
typedef __attribute__((ext_vector_type(4))) float f32x4;

struct Tables { float sinc[KF][DORD+1]; float cosc[KF][DORD+1]; };

// bf16 helpers: low/high halves of a packed uint, RNE pack
__device__ inline float bl(unsigned u) { return __uint_as_float(u << 16); }
__device__ inline float bh(unsigned u) { return __uint_as_float(u & 0xffff0000u); }
__device__ inline unsigned short bf16_rne(float x) {
    unsigned u = __float_as_uint(x);
    return (unsigned short)((u + 0x7fffu + ((u >> 16) & 1u)) >> 16);
}
__device__ inline unsigned pack_bf16x2(float a, float b) {
    return (unsigned)bf16_rne(a) | ((unsigned)bf16_rne(b) << 16);
}

// ---- coeff[d] = sum_k alpha[k]*sinc[k][d] + beta[k]*cosc[k][d] ----
__global__ void coeff_kernel(const float* __restrict__ alpha, const float* __restrict__ beta,
                             Tables tb, float* __restrict__ coeff) {
    int d = threadIdx.x;
    if (d <= DORD) {
        float c = 0.f;
        #pragma unroll
        for (int k = 0; k < KF; ++k)
            c += alpha[k] * tb.sinc[k][d] + beta[k] * tb.cosc[k][d];
        coeff[d] = c;
    }
}

// Buckets are 256 nodes wide (power of 2): bucket = v >> 8, offset = v & 255.
#define CHUNK 4096

// ---- pass 0: per-chunk dst-bucket AND src-bucket histograms (no global atomics) ----
__global__ __launch_bounds__(256) void hist_kernel(
    const int* __restrict__ src, const int* __restrict__ dst,
    int* __restrict__ histD, int* __restrict__ histS, int E, int nb) {
    __shared__ int hD[512];
    __shared__ int hS[512];
    for (int i = threadIdx.x; i < 512; i += 256) { hD[i] = 0; hS[i] = 0; }
    __syncthreads();
    int base = blockIdx.x * CHUNK;
    int end = base + CHUNK; if (end > E) end = E;
    for (int e = base + threadIdx.x; e < end; e += 256) {
        int s = src[e], d = dst[e];
        if (s != d) {
            atomicAdd(&hD[d >> 8], 1);
            atomicAdd(&hS[s >> 8], 1);
        }
    }
    __syncthreads();
    size_t ro = (size_t)blockIdx.x * 512;
    for (int i = threadIdx.x; i < nb; i += 256) {
        histD[ro + i] = hD[i];
        histS[ro + i] = hS[i];
    }
}

// ---- pass 0.5a: per-bucket exclusive scan over chunks (in place) + bucket totals ----
__global__ __launch_bounds__(512) void scanA_kernel(
    int* __restrict__ histD, int* __restrict__ histS,
    int* __restrict__ totD, int* __restrict__ totS, int nchunk, int nb) {
    __shared__ int tmp[512];
    int x = blockIdx.x;
    int* hist; int* tot; int b;
    if (x < nb) { hist = histD; tot = totD; b = x; }
    else        { hist = histS; tot = totS; b = x - nb; }
    int t = threadIdx.x;
    int carry = 0;
    for (int c0 = 0; c0 < nchunk; c0 += 512) {
        int c = c0 + t;
        tmp[t] = (c < nchunk) ? hist[(size_t)c * 512 + b] : 0;
        __syncthreads();
        for (int off = 1; off < 512; off <<= 1) {
            int add = (t >= off) ? tmp[t - off] : 0;
            __syncthreads();
            tmp[t] += add;
            __syncthreads();
        }
        if (c < nchunk) hist[(size_t)c * 512 + b] = carry + ((t > 0) ? tmp[t - 1] : 0);
        carry += tmp[511];
        __syncthreads();
    }
    if (t == 0) tot[b] = carry;
}

// ---- pass 0.5b: exclusive scan over bucket totals -> absolute bucket bases ----
__global__ __launch_bounds__(512) void scanB_kernel(
    const int* __restrict__ totD, const int* __restrict__ totS,
    int* __restrict__ offD, int* __restrict__ offS, int nb) {
    __shared__ int tmp[512];
    int t = threadIdx.x;
    tmp[t] = (t < nb) ? totD[t] : 0;
    __syncthreads();
    for (int off = 1; off < 512; off <<= 1) {
        int add = (t >= off) ? tmp[t - off] : 0;
        __syncthreads();
        tmp[t] += add;
        __syncthreads();
    }
    if (t < nb) offD[t] = (t > 0) ? tmp[t - 1] : 0;
    if (t == nb - 1) offD[nb] = tmp[t];
    __syncthreads();
    tmp[t] = (t < nb) ? totS[t] : 0;
    __syncthreads();
    for (int off = 1; off < 512; off <<= 1) {
        int add = (t >= off) ? tmp[t - off] : 0;
        __syncthreads();
        tmp[t] += add;
        __syncthreads();
    }
    if (t < nb) offS[t] = (t > 0) ? tmp[t - 1] : 0;
    if (t == nb - 1) offS[nb] = tmp[t];
}

// ---- pass 1: scatter with precomputed deterministic cursors (LDS atomics only) ----
__global__ __launch_bounds__(256) void scatter_kernel(
    const int* __restrict__ src, const int* __restrict__ dst,
    const int* __restrict__ histD, const int* __restrict__ histS,
    const int* __restrict__ offD, const int* __restrict__ offS,
    unsigned* __restrict__ binned, unsigned char* __restrict__ srcbin, int E, int nb) {
    __shared__ int cD[512];
    __shared__ int cS[512];
    size_t ro = (size_t)blockIdx.x * 512;
    for (int i = threadIdx.x; i < nb; i += 256) {
        cD[i] = offD[i] + histD[ro + i];
        cS[i] = offS[i] + histS[ro + i];
    }
    __syncthreads();
    int base = blockIdx.x * CHUNK;
    int end = base + CHUNK; if (end > E) end = E;
    for (int e = base + threadIdx.x; e < end; e += 256) {
        int s = src[e], d = dst[e];
        if (s != d) {
            int pD = atomicAdd(&cD[d >> 8], 1);
            binned[pD] = (unsigned)s | ((unsigned)(d & 255) << 24);
            int pS = atomicAdd(&cS[s >> 8], 1);
            srcbin[pS] = (unsigned char)(s & 255);
        }
    }
}

// ---- pass 2a: one block owns one bucket: local indeg, scan, row_ptr, col ----
__global__ __launch_bounds__(256) void bucket_csr_kernel(
    const unsigned* __restrict__ binned, const int* __restrict__ offD,
    int* __restrict__ row_ptr, int* __restrict__ col, int n, int nb) {
    int b = blockIdx.x;
    int e0 = offD[b], e1 = offD[b + 1];
    int d0 = b << 8;
    int dn = n - d0; if (dn > 256) dn = 256;
    __shared__ int ind[256];
    __shared__ int cur[256];
    int t = threadIdx.x;
    ind[t] = 0;
    __syncthreads();
    for (int e = e0 + t; e < e1; e += 256) {
        unsigned p = binned[e];
        atomicAdd(&ind[p >> 24], 1);
    }
    __syncthreads();
    for (int off = 1; off < 256; off <<= 1) {
        int add = (t >= off) ? ind[t - off] : 0;
        __syncthreads();
        ind[t] += add;
        __syncthreads();
    }
    if (t < dn) {
        int excl = (t > 0) ? ind[t - 1] : 0;
        row_ptr[d0 + t] = e0 + excl;
        cur[t] = e0 + excl;
    }
    if (b == 0 && t == 0) row_ptr[n] = offD[nb];
    __syncthreads();
    for (int e = e0 + t; e < e1; e += 256) {
        unsigned p = binned[e];
        int pos = atomicAdd(&cur[p >> 24], 1);
        col[pos] = (int)(p & 0xFFFFFFu);
    }
}

// ---- pass 2b: out-degree per node from src-binned bytes -> dinv ----
__global__ __launch_bounds__(256) void dinv_count_kernel(
    const unsigned char* __restrict__ srcbin, const int* __restrict__ offS,
    float* __restrict__ dinv, int n, int nb) {
    __shared__ int ind[256];
    int b = blockIdx.x;
    int t = threadIdx.x;
    ind[t] = 0;
    __syncthreads();
    int e0 = offS[b], e1 = offS[b + 1];
    for (int e = e0 + t; e < e1; e += 256)
        atomicAdd(&ind[srcbin[e]], 1);
    __syncthreads();
    int i = (b << 8) + t;
    if (i < n) {
        int c = ind[t];
        dinv[i] = (c > 0) ? (1.0f / sqrtf((float)c)) : 0.f;
    }
}

// ---- W1 -> bf16, transposed, K-padded: Wt[c][k] = bf16(W1[k][c]), k<500 else 0 ----
__global__ __launch_bounds__(256) void wprep_kernel(
    const float* __restrict__ W1, ushort_t* __restrict__ Wt) {
    int tid = blockIdx.x * 256 + threadIdx.x;       // 64*512 = 32768 elems
    if (tid >= 64 * KPAD) return;
    int kk = tid & (KPAD - 1);
    int c = tid >> 9;
    float v = (kk < FIN) ? W1[(size_t)kk * 64 + c] : 0.f;
    Wt[(size_t)c * KPAD + kk] = bf16_rne(v);
}

// ---- GEMM1 via MFMA bf16: H = relu(A[n,500] @ W[500,64] + b) ----
// 128 rows x 64 cols per block, 4 waves; mfma_f32_16x16x32_bf16.
// LDS tiles padded to 72 bf16/row (144B stride = 4-bank shift -> conflict-free-ish).
__global__ __launch_bounds__(256) void gemm1_mfma_kernel(
    const float* __restrict__ A, const ushort_t* __restrict__ Wt,
    const float* __restrict__ bias, float* __restrict__ H, int n) {
    __shared__ ushort_t sA[128][72];
    __shared__ ushort_t sB[64][72];
    int t = threadIdx.x;
    int w = t >> 6;            // wave 0..3 -> rows [w*32, w*32+32)
    int lane = t & 63;
    int lr = lane & 15;        // fragment row/col index
    int lg = lane >> 4;        // k-group (0..3)
    int rowBase = blockIdx.x * 128;

    f32x4 acc[2][4];
    #pragma unroll
    for (int r = 0; r < 2; ++r)
        #pragma unroll
        for (int c = 0; c < 4; ++c)
            acc[r][c] = (f32x4){0.f, 0.f, 0.f, 0.f};

    for (int kt = 0; kt < NKT; ++kt) {
        // stage A tile [128][64] fp32 -> bf16 (coalesced float4 reads)
        #pragma unroll
        for (int l = 0; l < 8; ++l) {
            int idx = t + l * 256;
            int r = idx >> 4;
            int kc = (idx & 15) * 4;
            int gr = rowBase + r;
            int gk = kt * 64 + kc;
            float4 v = make_float4(0.f, 0.f, 0.f, 0.f);
            if (gr < n) {
                if (gk + 3 < FIN) {
                    v = *(const float4*)(A + (size_t)gr * FIN + gk);
                } else {
                    float* vp = (float*)&v;
                    #pragma unroll
                    for (int j = 0; j < 4; ++j)
                        if (gk + j < FIN) vp[j] = A[(size_t)gr * FIN + gk + j];
                }
            }
            uint2 p;
            p.x = pack_bf16x2(v.x, v.y);
            p.y = pack_bf16x2(v.z, v.w);
            *(uint2*)&sA[r][kc] = p;
        }
        // stage Wt tile [64][64] bf16 (already converted/padded)
        #pragma unroll
        for (int l = 0; l < 2; ++l) {
            int idx = t + l * 256;
            int c = idx >> 3;
            int kc = (idx & 7) * 8;
            uint4 v = *(const uint4*)(Wt + (size_t)c * KPAD + kt * 64 + kc);
            *(uint4*)&sB[c][kc] = v;
        }
        __syncthreads();

        short8v af[2][2], bfr[4][2];
        #pragma unroll
        for (int r = 0; r < 2; ++r)
            #pragma unroll
            for (int h = 0; h < 2; ++h)
                af[r][h] = *(const short8v*)&sA[w * 32 + r * 16 + lr][h * 32 + lg * 8];
        #pragma unroll
        for (int c = 0; c < 4; ++c)
            #pragma unroll
            for (int h = 0; h < 2; ++h)
                bfr[c][h] = *(const short8v*)&sB[c * 16 + lr][h * 32 + lg * 8];
        #pragma unroll
        for (int r = 0; r < 2; ++r)
            #pragma unroll
            for (int c = 0; c < 4; ++c)
                #pragma unroll
                for (int h = 0; h < 2; ++h)
                    acc[r][c] = __builtin_amdgcn_mfma_f32_16x16x32_bf16(
                        af[r][h], bfr[c][h], acc[r][c], 0, 0, 0);
        __syncthreads();
    }

    // epilogue: D layout col=lane&15, row=(lane>>4)*4+i
    float bcol[4];
    #pragma unroll
    for (int c = 0; c < 4; ++c) bcol[c] = bias[c * 16 + lr];
    #pragma unroll
    for (int r = 0; r < 2; ++r) {
        #pragma unroll
        for (int c = 0; c < 4; ++c) {
            #pragma unroll
            for (int i = 0; i < 4; ++i) {
                int row = rowBase + w * 32 + r * 16 + lg * 4 + i;
                if (row < n)
                    H[(size_t)row * 64 + c * 16 + lr] = fmaxf(acc[r][c][i] + bcol[c], 0.f);
            }
        }
    }
}

// ---- GEMM2: X = H @ W2 + b2 ; out = (1+coeff[0])*X ; ty0 = bf16(dinv ⊙ X) ----
__global__ __launch_bounds__(256) void gemm2_kernel(
    const float* __restrict__ H, const float* __restrict__ W2,
    const float* __restrict__ b2, const float* __restrict__ coeff,
    const float* __restrict__ dinv, ushort_t* __restrict__ ty0,
    float* __restrict__ out, int n) {
    __shared__ float sW[64 * 64];
    __shared__ float sb[64];
    int t = threadIdx.x;
    for (int i = t; i < 4096; i += 256) sW[i] = W2[i];
    if (t < 64) sb[t] = b2[t];
    __syncthreads();
    float c0p1 = 1.f + coeff[0];
    int lane = t & 63;
    int wid = t >> 6;
    int r0 = blockIdx.x * 128;
    int rend = r0 + 128; if (rend > n) rend = n;
    for (int r = r0 + wid; r < rend; r += 4) {
        float hv = H[(size_t)r * 64 + lane];
        float dr = dinv[r];
        float acc = sb[lane];
        #pragma unroll
        for (int k = 0; k < 64; ++k)
            acc = fmaf(__shfl(hv, k, 64), sW[k * 64 + lane], acc);
        ty0[(size_t)r * 64 + lane] = bf16_rne(dr * acc);
        out[(size_t)r * 64 + lane] = c0p1 * acc;
    }
}

// ---- SpMM hop (dinv-folded, bf16 state): one wave per dst row.
__global__ __launch_bounds__(256) void spmm_kernel(
    const int* __restrict__ row_ptr, const int* __restrict__ col,
    const float* __restrict__ dinv, const ushort_t* __restrict__ tyin,
    ushort_t* __restrict__ tyout, float* __restrict__ out,
    const float* __restrict__ coeff, int d, int n, int fuse_lsm) {
    int wave = (blockIdx.x * blockDim.x + threadIdx.x) >> 6;
    if (wave >= n) return;
    int lane = threadIdx.x & 63;
    int sub = lane >> 4;       // 0..3: which edge within a group of 4
    int fl = lane & 15;        // feature group: elems 4*fl .. 4*fl+3
    int e0 = row_ptr[wave], e1 = row_ptr[wave + 1];
    float ax = 0.f, ay = 0.f, az = 0.f, aw = 0.f;
    int e = e0 + sub;
    for (; e + 12 < e1; e += 16) {
        int s0 = col[e], s1 = col[e + 4], s2 = col[e + 8], s3 = col[e + 12];
        uint2 p0 = *(const uint2*)(tyin + (size_t)s0 * 64 + fl * 4);
        uint2 p1 = *(const uint2*)(tyin + (size_t)s1 * 64 + fl * 4);
        uint2 p2 = *(const uint2*)(tyin + (size_t)s2 * 64 + fl * 4);
        uint2 p3 = *(const uint2*)(tyin + (size_t)s3 * 64 + fl * 4);
        ax += (bl(p0.x) + bl(p1.x)) + (bl(p2.x) + bl(p3.x));
        ay += (bh(p0.x) + bh(p1.x)) + (bh(p2.x) + bh(p3.x));
        az += (bl(p0.y) + bl(p1.y)) + (bl(p2.y) + bl(p3.y));
        aw += (bh(p0.y) + bh(p1.y)) + (bh(p2.y) + bh(p3.y));
    }
    for (; e < e1; e += 4) {
        int s = col[e];
        uint2 p = *(const uint2*)(tyin + (size_t)s * 64 + fl * 4);
        ax += bl(p.x); ay += bh(p.x); az += bl(p.y); aw += bh(p.y);
    }
    #pragma unroll
    for (int off = 16; off <= 32; off <<= 1) {
        ax += __shfl_xor(ax, off, 64);
        ay += __shfl_xor(ay, off, 64);
        az += __shfl_xor(az, off, 64);
        aw += __shfl_xor(aw, off, 64);
    }
    float dr = dinv[wave];
    float cd = coeff[d];
    float tx_x = -dr * ax, tx_y = -dr * ay, tx_z = -dr * az, tx_w = -dr * aw;
    float4 o = *(const float4*)(out + (size_t)wave * 64 + fl * 4);
    o.x += cd * tx_x; o.y += cd * tx_y; o.z += cd * tx_z; o.w += cd * tx_w;
    if (!fuse_lsm) {
        if (sub == 0) {
            uint2 ty;
            ty.x = pack_bf16x2(dr * tx_x, dr * tx_y);
            ty.y = pack_bf16x2(dr * tx_z, dr * tx_w);
            *(uint2*)(tyout + (size_t)wave * 64 + fl * 4) = ty;
            *(float4*)(out + (size_t)wave * 64 + fl * 4) = o;
        }
    } else {
        float m = fmaxf(fmaxf(o.x, o.y), fmaxf(o.z, o.w));
        #pragma unroll
        for (int off = 1; off < 16; off <<= 1) m = fmaxf(m, __shfl_xor(m, off, 64));
        float s4 = expf(o.x - m) + expf(o.y - m) + expf(o.z - m) + expf(o.w - m);
        #pragma unroll
        for (int off = 1; off < 16; off <<= 1) s4 += __shfl_xor(s4, off, 64);
        float lse = m + logf(s4);
        o.x -= lse; o.y -= lse; o.z -= lse; o.w -= lse;
        if (sub == 0)
            *(float4*)(out + (size_t)wave * 64 + fl * 4) = o;
    }
}

extern "C" void kernel_launch(void* const* d_in, const int* in_sizes, int n_in,
                              void* d_out, int out_size, void* d_ws, size_t ws_size,
                              hipStream_t stream) {
    const float* feature = (const float*)d_in[0];
    const int*   edges   = (const int*)d_in[1];
    const float* W1      = (const float*)d_in[2];
    const float* b1      = (const float*)d_in[3];
    const float* W2      = (const float*)d_in[4];
    const float* b2      = (const float*)d_in[5];
    const float* alpha   = (const float*)d_in[6];
    const float* beta    = (const float*)d_in[7];
    float* out = (float*)d_out;

    const int n = in_sizes[0] / FIN;      // 100000
    const int E = in_sizes[1] / 2;        // 3200000
    const int* src = edges;
    const int* dst = edges + E;

    const int nb = (n + 255) >> 8;        // 391 buckets of 256 nodes
    const int nchunk = (E + CHUNK - 1) / CHUNK;

    // ---- workspace layout (256B aligned) ----
    char* ws = (char*)d_ws;
    size_t off = 0;
    auto alloc = [&](size_t bytes) { size_t o = off; off = (off + bytes + 255) & ~(size_t)255; return o; };
    float*         coeff   = (float*)        (ws + alloc(64 * 4));
    float*         dinv    = (float*)        (ws + alloc((size_t)n * 4));
    int*           row_ptr = (int*)          (ws + alloc(((size_t)n + 1) * 4));
    int*           offD    = (int*)          (ws + alloc(513 * 4));
    int*           offS    = (int*)          (ws + alloc(513 * 4));
    int*           totD    = (int*)          (ws + alloc(512 * 4));
    int*           totS    = (int*)          (ws + alloc(512 * 4));
    ushort_t*      Wt      = (ushort_t*)     (ws + alloc((size_t)64 * KPAD * 2));
    int*           histD   = (int*)          (ws + alloc((size_t)nchunk * 512 * 4));
    int*           histS   = (int*)          (ws + alloc((size_t)nchunk * 512 * 4));
    int*           col     = (int*)          (ws + alloc((size_t)E * 4));
    unsigned*      binned  = (unsigned*)     (ws + alloc((size_t)E * 4));
    unsigned char* srcbin  = (unsigned char*)(ws + alloc((size_t)E));
    float*         H       = (float*)        (ws + alloc((size_t)n * 64 * 4));
    ushort_t*      TyA     = (ushort_t*)     (ws + alloc((size_t)n * 64 * 2));
    ushort_t*      TyB     = (ushort_t*)     (ws + alloc((size_t)n * 64 * 2));

    // ---- host-side Taylor tables (deterministic, recomputed every call) ----
    Tables tb;
    for (int k = 0; k < KF; ++k) {
        double x = M_PI * (double)(k + 1);   // OMEGA = 1
        double p = 1.0, f = 1.0;
        for (int o = 0; o <= DORD; ++o) {
            if (o > 0) { p *= x; f *= (double)o; }
            double v = p / f;
            tb.cosc[k][o] = (o % 2 == 0) ? (float)((((o / 2) % 2 == 0) ? 1.0 : -1.0) * v) : 0.f;
            tb.sinc[k][o] = (o % 2 == 1) ? (float)(((((o - 1) / 2) % 2 == 0) ? 1.0 : -1.0) * v) : 0.f;
        }
    }

    coeff_kernel<<<1, 64, 0, stream>>>(alpha, beta, tb, coeff);
    wprep_kernel<<<(64 * KPAD + 255) / 256, 256, 0, stream>>>(W1, Wt);

    hist_kernel<<<nchunk, 256, 0, stream>>>(src, dst, histD, histS, E, nb);
    scanA_kernel<<<2 * nb, 512, 0, stream>>>(histD, histS, totD, totS, nchunk, nb);
    scanB_kernel<<<1, 512, 0, stream>>>(totD, totS, offD, offS, nb);
    scatter_kernel<<<nchunk, 256, 0, stream>>>(src, dst, histD, histS, offD, offS,
                                               binned, srcbin, E, nb);
    bucket_csr_kernel<<<nb, 256, 0, stream>>>(binned, offD, row_ptr, col, n, nb);
    dinv_count_kernel<<<nb, 256, 0, stream>>>(srcbin, offS, dinv, n, nb);

    gemm1_mfma_kernel<<<(n + 127) / 128, 256, 0, stream>>>(feature, Wt, b1, H, n);
    gemm2_kernel<<<(n + 127) / 128, 256, 0, stream>>>(H, W2, b2, coeff, dinv, TyA, out, n);

    const ushort_t* tin = TyA;
    ushort_t* bufs[2] = { TyB, TyA };
    for (int d = 1; d <= DORD; ++d) {
        ushort_t* tout = bufs[(d - 1) & 1];
        spmm_kernel<<<(n + 3) / 4, 256, 0, stream>>>(row_ptr, col, dinv, tin, tout, out,
                                                     coeff, d, n, d == DORD ? 1 : 0);
        tin = tout;
    }
}

// Round 5
// 1181.319 us; speedup vs baseline: 1.1651x; 1.0726x over previous
//
#include <hip/hip_runtime.h>
#include <math.h>

#define NN 100000
#define FIN 500
#define HIDN 64
#define KF 5
#define DORD 10
#define KPAD 512
#define NKT 8

typedef unsigned short ushort_t;
typedef __attribute__((ext_vector_type(8))) short short8v;
typedef __attribute__((ext_vector_type(4))) float f32x4;

struct Tables { float sinc[KF][DORD+1]; float cosc[KF][DORD+1]; };

// bf16 helpers: low/high halves of a packed uint, RNE pack
__device__ inline float bl(unsigned u) { return __uint_as_float(u << 16); }
__device__ inline float bh(unsigned u) { return __uint_as_float(u & 0xffff0000u); }
__device__ inline unsigned short bf16_rne(float x) {
    unsigned u = __float_as_uint(x);
    return (unsigned short)((u + 0x7fffu + ((u >> 16) & 1u)) >> 16);
}
__device__ inline unsigned pack_bf16x2(float a, float b) {
    return (unsigned)bf16_rne(a) | ((unsigned)bf16_rne(b) << 16);
}

// ---- coeff[d] = sum_k alpha[k]*sinc[k][d] + beta[k]*cosc[k][d] ----
__global__ void coeff_kernel(const float* __restrict__ alpha, const float* __restrict__ beta,
                             Tables tb, float* __restrict__ coeff) {
    int d = threadIdx.x;
    if (d <= DORD) {
        float c = 0.f;
        #pragma unroll
        for (int k = 0; k < KF; ++k)
            c += alpha[k] * tb.sinc[k][d] + beta[k] * tb.cosc[k][d];
        coeff[d] = c;
    }
}

// Buckets are 256 nodes wide (power of 2): bucket = v >> 8, offset = v & 255.
#define CHUNK 4096

// ---- pass 0: per-chunk dst-bucket AND src-bucket histograms (no global atomics) ----
__global__ __launch_bounds__(256) void hist_kernel(
    const int* __restrict__ src, const int* __restrict__ dst,
    int* __restrict__ histD, int* __restrict__ histS, int E, int nb) {
    __shared__ int hD[512];
    __shared__ int hS[512];
    for (int i = threadIdx.x; i < 512; i += 256) { hD[i] = 0; hS[i] = 0; }
    __syncthreads();
    int base = blockIdx.x * CHUNK;
    int end = base + CHUNK; if (end > E) end = E;
    for (int e = base + threadIdx.x; e < end; e += 256) {
        int s = src[e], d = dst[e];
        if (s != d) {
            atomicAdd(&hD[d >> 8], 1);
            atomicAdd(&hS[s >> 8], 1);
        }
    }
    __syncthreads();
    size_t ro = (size_t)blockIdx.x * 512;
    for (int i = threadIdx.x; i < nb; i += 256) {
        histD[ro + i] = hD[i];
        histS[ro + i] = hS[i];
    }
}

// ---- pass 0.5a: per-bucket exclusive scan over chunks (in place) + bucket totals ----
__global__ __launch_bounds__(512) void scanA_kernel(
    int* __restrict__ histD, int* __restrict__ histS,
    int* __restrict__ totD, int* __restrict__ totS, int nchunk, int nb) {
    __shared__ int tmp[512];
    int x = blockIdx.x;
    int* hist; int* tot; int b;
    if (x < nb) { hist = histD; tot = totD; b = x; }
    else        { hist = histS; tot = totS; b = x - nb; }
    int t = threadIdx.x;
    int carry = 0;
    for (int c0 = 0; c0 < nchunk; c0 += 512) {
        int c = c0 + t;
        tmp[t] = (c < nchunk) ? hist[(size_t)c * 512 + b] : 0;
        __syncthreads();
        for (int off = 1; off < 512; off <<= 1) {
            int add = (t >= off) ? tmp[t - off] : 0;
            __syncthreads();
            tmp[t] += add;
            __syncthreads();
        }
        if (c < nchunk) hist[(size_t)c * 512 + b] = carry + ((t > 0) ? tmp[t - 1] : 0);
        carry += tmp[511];
        __syncthreads();
    }
    if (t == 0) tot[b] = carry;
}

// ---- pass 0.5b: exclusive scan over bucket totals -> absolute bucket bases ----
__global__ __launch_bounds__(512) void scanB_kernel(
    const int* __restrict__ totD, const int* __restrict__ totS,
    int* __restrict__ offD, int* __restrict__ offS, int nb) {
    __shared__ int tmp[512];
    int t = threadIdx.x;
    tmp[t] = (t < nb) ? totD[t] : 0;
    __syncthreads();
    for (int off = 1; off < 512; off <<= 1) {
        int add = (t >= off) ? tmp[t - off] : 0;
        __syncthreads();
        tmp[t] += add;
        __syncthreads();
    }
    if (t < nb) offD[t] = (t > 0) ? tmp[t - 1] : 0;
    if (t == nb - 1) offD[nb] = tmp[t];
    __syncthreads();
    tmp[t] = (t < nb) ? totS[t] : 0;
    __syncthreads();
    for (int off = 1; off < 512; off <<= 1) {
        int add = (t >= off) ? tmp[t - off] : 0;
        __syncthreads();
        tmp[t] += add;
        __syncthreads();
    }
    if (t < nb) offS[t] = (t > 0) ? tmp[t - 1] : 0;
    if (t == nb - 1) offS[nb] = tmp[t];
}

// ---- pass 1: scatter with precomputed deterministic cursors (LDS atomics only) ----
__global__ __launch_bounds__(256) void scatter_kernel(
    const int* __restrict__ src, const int* __restrict__ dst,
    const int* __restrict__ histD, const int* __restrict__ histS,
    const int* __restrict__ offD, const int* __restrict__ offS,
    unsigned* __restrict__ binned, unsigned char* __restrict__ srcbin, int E, int nb) {
    __shared__ int cD[512];
    __shared__ int cS[512];
    size_t ro = (size_t)blockIdx.x * 512;
    for (int i = threadIdx.x; i < nb; i += 256) {
        cD[i] = offD[i] + histD[ro + i];
        cS[i] = offS[i] + histS[ro + i];
    }
    __syncthreads();
    int base = blockIdx.x * CHUNK;
    int end = base + CHUNK; if (end > E) end = E;
    for (int e = base + threadIdx.x; e < end; e += 256) {
        int s = src[e], d = dst[e];
        if (s != d) {
            int pD = atomicAdd(&cD[d >> 8], 1);
            binned[pD] = (unsigned)s | ((unsigned)(d & 255) << 24);
            int pS = atomicAdd(&cS[s >> 8], 1);
            srcbin[pS] = (unsigned char)(s & 255);
        }
    }
}

// ---- pass 2a: one block owns one bucket: local indeg, scan, row_ptr, col ----
__global__ __launch_bounds__(256) void bucket_csr_kernel(
    const unsigned* __restrict__ binned, const int* __restrict__ offD,
    int* __restrict__ row_ptr, int* __restrict__ col, int n, int nb) {
    int b = blockIdx.x;
    int e0 = offD[b], e1 = offD[b + 1];
    int d0 = b << 8;
    int dn = n - d0; if (dn > 256) dn = 256;
    __shared__ int ind[256];
    __shared__ int cur[256];
    int t = threadIdx.x;
    ind[t] = 0;
    __syncthreads();
    for (int e = e0 + t; e < e1; e += 256) {
        unsigned p = binned[e];
        atomicAdd(&ind[p >> 24], 1);
    }
    __syncthreads();
    for (int off = 1; off < 256; off <<= 1) {
        int add = (t >= off) ? ind[t - off] : 0;
        __syncthreads();
        ind[t] += add;
        __syncthreads();
    }
    if (t < dn) {
        int excl = (t > 0) ? ind[t - 1] : 0;
        row_ptr[d0 + t] = e0 + excl;
        cur[t] = e0 + excl;
    }
    if (b == 0 && t == 0) row_ptr[n] = offD[nb];
    __syncthreads();
    for (int e = e0 + t; e < e1; e += 256) {
        unsigned p = binned[e];
        int pos = atomicAdd(&cur[p >> 24], 1);
        col[pos] = (int)(p & 0xFFFFFFu);
    }
}

// ---- pass 2b: out-degree per node from src-binned bytes -> dinv ----
__global__ __launch_bounds__(256) void dinv_count_kernel(
    const unsigned char* __restrict__ srcbin, const int* __restrict__ offS,
    float* __restrict__ dinv, int n, int nb) {
    __shared__ int ind[256];
    int b = blockIdx.x;
    int t = threadIdx.x;
    ind[t] = 0;
    __syncthreads();
    int e0 = offS[b], e1 = offS[b + 1];
    for (int e = e0 + t; e < e1; e += 256)
        atomicAdd(&ind[srcbin[e]], 1);
    __syncthreads();
    int i = (b << 8) + t;
    if (i < n) {
        int c = ind[t];
        dinv[i] = (c > 0) ? (1.0f / sqrtf((float)c)) : 0.f;
    }
}

// ---- W1 -> bf16, transposed, K-padded: Wt[c][k] = bf16(W1[k][c]), k<500 else 0 ----
__global__ __launch_bounds__(256) void wprep_kernel(
    const float* __restrict__ W1, ushort_t* __restrict__ Wt) {
    int tid = blockIdx.x * 256 + threadIdx.x;       // 64*512 = 32768 elems
    if (tid >= 64 * KPAD) return;
    int kk = tid & (KPAD - 1);
    int c = tid >> 9;
    float v = (kk < FIN) ? W1[(size_t)kk * 64 + c] : 0.f;
    Wt[(size_t)c * KPAD + kk] = bf16_rne(v);
}

// ---- GEMM1 via MFMA bf16: H = relu(A[n,500] @ W[500,64] + b) ----
__global__ __launch_bounds__(256) void gemm1_mfma_kernel(
    const float* __restrict__ A, const ushort_t* __restrict__ Wt,
    const float* __restrict__ bias, float* __restrict__ H, int n) {
    __shared__ ushort_t sA[128][72];
    __shared__ ushort_t sB[64][72];
    int t = threadIdx.x;
    int w = t >> 6;            // wave 0..3 -> rows [w*32, w*32+32)
    int lane = t & 63;
    int lr = lane & 15;        // fragment row/col index
    int lg = lane >> 4;        // k-group (0..3)
    int rowBase = blockIdx.x * 128;

    f32x4 acc[2][4];
    #pragma unroll
    for (int r = 0; r < 2; ++r)
        #pragma unroll
        for (int c = 0; c < 4; ++c)
            acc[r][c] = (f32x4){0.f, 0.f, 0.f, 0.f};

    for (int kt = 0; kt < NKT; ++kt) {
        #pragma unroll
        for (int l = 0; l < 8; ++l) {
            int idx = t + l * 256;
            int r = idx >> 4;
            int kc = (idx & 15) * 4;
            int gr = rowBase + r;
            int gk = kt * 64 + kc;
            float4 v = make_float4(0.f, 0.f, 0.f, 0.f);
            if (gr < n) {
                if (gk + 3 < FIN) {
                    v = *(const float4*)(A + (size_t)gr * FIN + gk);
                } else {
                    float* vp = (float*)&v;
                    #pragma unroll
                    for (int j = 0; j < 4; ++j)
                        if (gk + j < FIN) vp[j] = A[(size_t)gr * FIN + gk + j];
                }
            }
            uint2 p;
            p.x = pack_bf16x2(v.x, v.y);
            p.y = pack_bf16x2(v.z, v.w);
            *(uint2*)&sA[r][kc] = p;
        }
        #pragma unroll
        for (int l = 0; l < 2; ++l) {
            int idx = t + l * 256;
            int c = idx >> 3;
            int kc = (idx & 7) * 8;
            uint4 v = *(const uint4*)(Wt + (size_t)c * KPAD + kt * 64 + kc);
            *(uint4*)&sB[c][kc] = v;
        }
        __syncthreads();

        short8v af[2][2], bfr[4][2];
        #pragma unroll
        for (int r = 0; r < 2; ++r)
            #pragma unroll
            for (int h = 0; h < 2; ++h)
                af[r][h] = *(const short8v*)&sA[w * 32 + r * 16 + lr][h * 32 + lg * 8];
        #pragma unroll
        for (int c = 0; c < 4; ++c)
            #pragma unroll
            for (int h = 0; h < 2; ++h)
                bfr[c][h] = *(const short8v*)&sB[c * 16 + lr][h * 32 + lg * 8];
        #pragma unroll
        for (int r = 0; r < 2; ++r)
            #pragma unroll
            for (int c = 0; c < 4; ++c)
                #pragma unroll
                for (int h = 0; h < 2; ++h)
                    acc[r][c] = __builtin_amdgcn_mfma_f32_16x16x32_bf16(
                        af[r][h], bfr[c][h], acc[r][c], 0, 0, 0);
        __syncthreads();
    }

    float bcol[4];
    #pragma unroll
    for (int c = 0; c < 4; ++c) bcol[c] = bias[c * 16 + lr];
    #pragma unroll
    for (int r = 0; r < 2; ++r) {
        #pragma unroll
        for (int c = 0; c < 4; ++c) {
            #pragma unroll
            for (int i = 0; i < 4; ++i) {
                int row = rowBase + w * 32 + r * 16 + lg * 4 + i;
                if (row < n)
                    H[(size_t)row * 64 + c * 16 + lr] = fmaxf(acc[r][c][i] + bcol[c], 0.f);
            }
        }
    }
}

// ---- GEMM2: X = H @ W2 + b2 ; out = (1+coeff[0])*X ; ty0 = bf16(dinv ⊙ X) ----
__global__ __launch_bounds__(256) void gemm2_kernel(
    const float* __restrict__ H, const float* __restrict__ W2,
    const float* __restrict__ b2, const float* __restrict__ coeff,
    const float* __restrict__ dinv, ushort_t* __restrict__ ty0,
    float* __restrict__ out, int n) {
    __shared__ float sW[64 * 64];
    __shared__ float sb[64];
    int t = threadIdx.x;
    for (int i = t; i < 4096; i += 256) sW[i] = W2[i];
    if (t < 64) sb[t] = b2[t];
    __syncthreads();
    float c0p1 = 1.f + coeff[0];
    int lane = t & 63;
    int wid = t >> 6;
    int r0 = blockIdx.x * 128;
    int rend = r0 + 128; if (rend > n) rend = n;
    for (int r = r0 + wid; r < rend; r += 4) {
        float hv = H[(size_t)r * 64 + lane];
        float dr = dinv[r];
        float acc = sb[lane];
        #pragma unroll
        for (int k = 0; k < 64; ++k)
            acc = fmaf(__shfl(hv, k, 64), sW[k * 64 + lane], acc);
        ty0[(size_t)r * 64 + lane] = bf16_rne(dr * acc);
        out[(size_t)r * 64 + lane] = c0p1 * acc;
    }
}

// ---- SpMM hop (fused out-accumulate, fp32 tx): one wave per dst row.
// 8 edge-slots x 8 feature-lanes, uint4 (16B) gathers: 0.25 VMEM instr/edge.
// tx = -dinv * sum(ty_in[src]); out += coeff[d]*tx (fp32); ty_out = bf16(dinv*tx).
__global__ __launch_bounds__(256) void spmm_kernel(
    const int* __restrict__ row_ptr, const int* __restrict__ col,
    const float* __restrict__ dinv, const ushort_t* __restrict__ tyin,
    ushort_t* __restrict__ tyout, float* __restrict__ out,
    const float* __restrict__ coeff, int d, int n, int fuse_lsm) {
    int wave = (blockIdx.x * blockDim.x + threadIdx.x) >> 6;
    if (wave >= n) return;
    int lane = threadIdx.x & 63;
    int sub = lane >> 3;       // 0..7: edge slot
    int fl = lane & 7;         // feature block: feats [fl*8, fl*8+8)
    int e0 = row_ptr[wave], e1 = row_ptr[wave + 1];
    float a0 = 0.f, a1 = 0.f, a2 = 0.f, a3 = 0.f;
    float a4 = 0.f, a5 = 0.f, a6 = 0.f, a7 = 0.f;
    int e = e0 + sub;
    for (; e + 8 < e1; e += 16) {
        int s0 = col[e], s1 = col[e + 8];
        uint4 p0 = *(const uint4*)(tyin + (size_t)s0 * 64 + fl * 8);
        uint4 p1 = *(const uint4*)(tyin + (size_t)s1 * 64 + fl * 8);
        a0 += bl(p0.x) + bl(p1.x); a1 += bh(p0.x) + bh(p1.x);
        a2 += bl(p0.y) + bl(p1.y); a3 += bh(p0.y) + bh(p1.y);
        a4 += bl(p0.z) + bl(p1.z); a5 += bh(p0.z) + bh(p1.z);
        a6 += bl(p0.w) + bl(p1.w); a7 += bh(p0.w) + bh(p1.w);
    }
    if (e < e1) {
        int s = col[e];
        uint4 p = *(const uint4*)(tyin + (size_t)s * 64 + fl * 8);
        a0 += bl(p.x); a1 += bh(p.x); a2 += bl(p.y); a3 += bh(p.y);
        a4 += bl(p.z); a5 += bh(p.z); a6 += bl(p.w); a7 += bh(p.w);
    }
    #pragma unroll
    for (int off = 8; off <= 32; off <<= 1) {
        a0 += __shfl_xor(a0, off, 64); a1 += __shfl_xor(a1, off, 64);
        a2 += __shfl_xor(a2, off, 64); a3 += __shfl_xor(a3, off, 64);
        a4 += __shfl_xor(a4, off, 64); a5 += __shfl_xor(a5, off, 64);
        a6 += __shfl_xor(a6, off, 64); a7 += __shfl_xor(a7, off, 64);
    }
    float dr = dinv[wave];
    float cd = coeff[d];
    float t0 = -dr * a0, t1 = -dr * a1, t2 = -dr * a2, t3 = -dr * a3;
    float t4 = -dr * a4, t5 = -dr * a5, t6 = -dr * a6, t7 = -dr * a7;
    if (!fuse_lsm) {
        if (sub == 0) {
            float4 o0 = *(const float4*)(out + (size_t)wave * 64 + fl * 8);
            float4 o1 = *(const float4*)(out + (size_t)wave * 64 + fl * 8 + 4);
            o0.x += cd * t0; o0.y += cd * t1; o0.z += cd * t2; o0.w += cd * t3;
            o1.x += cd * t4; o1.y += cd * t5; o1.z += cd * t6; o1.w += cd * t7;
            *(float4*)(out + (size_t)wave * 64 + fl * 8) = o0;
            *(float4*)(out + (size_t)wave * 64 + fl * 8 + 4) = o1;
            uint4 ty;
            ty.x = pack_bf16x2(dr * t0, dr * t1);
            ty.y = pack_bf16x2(dr * t2, dr * t3);
            ty.z = pack_bf16x2(dr * t4, dr * t5);
            ty.w = pack_bf16x2(dr * t6, dr * t7);
            *(uint4*)(tyout + (size_t)wave * 64 + fl * 8) = ty;
        }
    } else {
        float4 o0 = *(const float4*)(out + (size_t)wave * 64 + fl * 8);
        float4 o1 = *(const float4*)(out + (size_t)wave * 64 + fl * 8 + 4);
        o0.x += cd * t0; o0.y += cd * t1; o0.z += cd * t2; o0.w += cd * t3;
        o1.x += cd * t4; o1.y += cd * t5; o1.z += cd * t6; o1.w += cd * t7;
        float m = fmaxf(fmaxf(fmaxf(o0.x, o0.y), fmaxf(o0.z, o0.w)),
                        fmaxf(fmaxf(o1.x, o1.y), fmaxf(o1.z, o1.w)));
        #pragma unroll
        for (int off = 1; off < 8; off <<= 1) m = fmaxf(m, __shfl_xor(m, off, 64));
        float se = expf(o0.x - m) + expf(o0.y - m) + expf(o0.z - m) + expf(o0.w - m)
                 + expf(o1.x - m) + expf(o1.y - m) + expf(o1.z - m) + expf(o1.w - m);
        #pragma unroll
        for (int off = 1; off < 8; off <<= 1) se += __shfl_xor(se, off, 64);
        float lse = m + logf(se);
        o0.x -= lse; o0.y -= lse; o0.z -= lse; o0.w -= lse;
        o1.x -= lse; o1.y -= lse; o1.z -= lse; o1.w -= lse;
        if (sub == 0) {
            *(float4*)(out + (size_t)wave * 64 + fl * 8) = o0;
            *(float4*)(out + (size_t)wave * 64 + fl * 8 + 4) = o1;
        }
    }
}

extern "C" void kernel_launch(void* const* d_in, const int* in_sizes, int n_in,
                              void* d_out, int out_size, void* d_ws, size_t ws_size,
                              hipStream_t stream) {
    const float* feature = (const float*)d_in[0];
    const int*   edges   = (const int*)d_in[1];
    const float* W1      = (const float*)d_in[2];
    const float* b1      = (const float*)d_in[3];
    const float* W2      = (const float*)d_in[4];
    const float* b2      = (const float*)d_in[5];
    const float* alpha   = (const float*)d_in[6];
    const float* beta    = (const float*)d_in[7];
    float* out = (float*)d_out;

    const int n = in_sizes[0] / FIN;      // 100000
    const int E = in_sizes[1] / 2;        // 3200000
    const int* src = edges;
    const int* dst = edges + E;

    const int nb = (n + 255) >> 8;        // 391 buckets of 256 nodes
    const int nchunk = (E + CHUNK - 1) / CHUNK;
    const size_t n64 = (size_t)n * 64;

    // ---- workspace layout (256B aligned) ----
    char* ws = (char*)d_ws;
    size_t off = 0;
    auto alloc = [&](size_t bytes) { size_t o = off; off = (off + bytes + 255) & ~(size_t)255; return o; };
    float*         coeff   = (float*)        (ws + alloc(64 * 4));
    float*         dinv    = (float*)        (ws + alloc((size_t)n * 4));
    int*           row_ptr = (int*)          (ws + alloc(((size_t)n + 1) * 4));
    int*           offD    = (int*)          (ws + alloc(513 * 4));
    int*           offS    = (int*)          (ws + alloc(513 * 4));
    int*           totD    = (int*)          (ws + alloc(512 * 4));
    int*           totS    = (int*)          (ws + alloc(512 * 4));
    ushort_t*      Wt      = (ushort_t*)     (ws + alloc((size_t)64 * KPAD * 2));
    int*           histD   = (int*)          (ws + alloc((size_t)nchunk * 512 * 4));
    int*           histS   = (int*)          (ws + alloc((size_t)nchunk * 512 * 4));
    int*           col     = (int*)          (ws + alloc((size_t)E * 4));
    unsigned*      binned  = (unsigned*)     (ws + alloc((size_t)E * 4));
    unsigned char* srcbin  = (unsigned char*)(ws + alloc((size_t)E));
    float*         H       = (float*)        (ws + alloc(n64 * 4));
    ushort_t*      TyA     = (ushort_t*)     (ws + alloc(n64 * 2));
    ushort_t*      TyB     = (ushort_t*)     (ws + alloc(n64 * 2));

    // ---- host-side Taylor tables (deterministic, recomputed every call) ----
    Tables tb;
    for (int k = 0; k < KF; ++k) {
        double x = M_PI * (double)(k + 1);   // OMEGA = 1
        double p = 1.0, f = 1.0;
        for (int o = 0; o <= DORD; ++o) {
            if (o > 0) { p *= x; f *= (double)o; }
            double v = p / f;
            tb.cosc[k][o] = (o % 2 == 0) ? (float)((((o / 2) % 2 == 0) ? 1.0 : -1.0) * v) : 0.f;
            tb.sinc[k][o] = (o % 2 == 1) ? (float)(((((o - 1) / 2) % 2 == 0) ? 1.0 : -1.0) * v) : 0.f;
        }
    }

    coeff_kernel<<<1, 64, 0, stream>>>(alpha, beta, tb, coeff);
    wprep_kernel<<<(64 * KPAD + 255) / 256, 256, 0, stream>>>(W1, Wt);

    hist_kernel<<<nchunk, 256, 0, stream>>>(src, dst, histD, histS, E, nb);
    scanA_kernel<<<2 * nb, 512, 0, stream>>>(histD, histS, totD, totS, nchunk, nb);
    scanB_kernel<<<1, 512, 0, stream>>>(totD, totS, offD, offS, nb);
    scatter_kernel<<<nchunk, 256, 0, stream>>>(src, dst, histD, histS, offD, offS,
                                               binned, srcbin, E, nb);
    bucket_csr_kernel<<<nb, 256, 0, stream>>>(binned, offD, row_ptr, col, n, nb);
    dinv_count_kernel<<<nb, 256, 0, stream>>>(srcbin, offS, dinv, n, nb);

    gemm1_mfma_kernel<<<(n + 127) / 128, 256, 0, stream>>>(feature, Wt, b1, H, n);
    gemm2_kernel<<<(n + 127) / 128, 256, 0, stream>>>(H, W2, b2, coeff, dinv, TyA, out, n);

    const ushort_t* tin = TyA;
    ushort_t* bufs[2] = { TyB, TyA };
    for (int d = 1; d <= DORD; ++d) {
        ushort_t* tout = bufs[(d - 1) & 1];
        spmm_kernel<<<(n + 3) / 4, 256, 0, stream>>>(row_ptr, col, dinv, tin, tout, out,
                                                     coeff, d, n, d == DORD ? 1 : 0);
        tin = tout;
    }
}